// Round 2
// baseline (293.918 us; speedup 1.0000x reference)
//
#include <hip/hip_runtime.h>
#include <hip/hip_bf16.h>

#define Bsz 8
#define Ssz 4096
#define Dsz 128

typedef short bf16x8 __attribute__((ext_vector_type(8)));
typedef float f32x4 __attribute__((ext_vector_type(4)));

__device__ __forceinline__ short f2bf(float f) {
  union { float f; unsigned u; } v; v.f = f;
  unsigned r = v.u + 0x7fffu + ((v.u >> 16) & 1u);
  return (short)(r >> 16);
}

// ---------------- Projection: X[BS,128] @ W[3][128][128] -> Qb(*log2e), Kb, Vt ----------------
// Inputs are fp32 (reference dtype). Outputs bf16 for the MFMA attention stage.
// Block: 256 threads, 16 rows of X. fp32 accumulate.
__global__ __launch_bounds__(256) void proj_kernel(
    const float* __restrict__ x, const float* __restrict__ w,
    short* __restrict__ Qb, short* __restrict__ Kb, short* __restrict__ Vt) {
  __shared__ float xt[Dsz * 20];  // xt[d][r], stride 20 (16B-aligned rows, few conflicts)
  const int t = threadIdx.x;
  const long base_row = (long)blockIdx.x * 16;

  #pragma unroll
  for (int p = 0; p < 8; ++p) {
    int idx = p * 256 + t;
    int r = idx >> 7, d = idx & 127;
    xt[d * 20 + r] = x[(base_row + r) * Dsz + d];
  }
  __syncthreads();

  const int e = t & 127, h = t >> 7;
  float accq[8], acck[8], accv[8];
  #pragma unroll
  for (int j = 0; j < 8; ++j) { accq[j] = 0.f; acck[j] = 0.f; accv[j] = 0.f; }
  const float* wqp = w;
  const float* wkp = w + Dsz * Dsz;
  const float* wvp = w + 2 * Dsz * Dsz;

  #pragma unroll 4
  for (int d = 0; d < Dsz; ++d) {
    float a  = wqp[d * Dsz + e];
    float bb = wkp[d * Dsz + e];
    float c  = wvp[d * Dsz + e];
    const float* xr = &xt[d * 20 + h * 8];
    #pragma unroll
    for (int j = 0; j < 8; ++j) {
      float xv = xr[j];
      accq[j] = fmaf(xv, a,  accq[j]);
      acck[j] = fmaf(xv, bb, acck[j]);
      accv[j] = fmaf(xv, c,  accv[j]);
    }
  }

  const float LOG2E = 1.44269504088896340736f;
  #pragma unroll
  for (int j = 0; j < 8; ++j) {
    long R = base_row + h * 8 + j;
    Qb[R * Dsz + e] = f2bf(accq[j] * LOG2E);  // fold log2(e) so attn uses exp2 directly
    Kb[R * Dsz + e] = f2bf(acck[j]);
  }
  // V stored transposed: Vt[(b*128 + d)*4096 + s]; thread owns 8 consecutive s -> one 16B store
  int b = (int)(base_row >> 12);
  int s_in_b = (int)(base_row & 4095) + h * 8;
  short vp[8];
  #pragma unroll
  for (int j = 0; j < 8; ++j) vp[j] = f2bf(accv[j]);
  *(bf16x8*)&Vt[((long)(b * Dsz + e)) * Ssz + s_in_b] = *(const bf16x8*)vp;
}

// ---------------- Attention ----------------
// grid (8, 32): blockIdx.x = batch (XCD affinity), blockIdx.y = q-tile of 128.
// 4 waves, 2x2 partition: wave (wq,wk): QK^T -> S[64q x 64k]; PV -> O[64q x 64d].
// LDS: kv tile (K rows, then V^T rows) 32KB + P tile 32KB, 16B-granule XOR swizzle.
#define SWZ(row, g) (((row) << 7) + ((((g) ^ ((row) & 15))) << 3))

__global__ __launch_bounds__(256, 1) void attn_kernel(
    const short* __restrict__ Qb, const short* __restrict__ Kb,
    const short* __restrict__ Vt, float* __restrict__ acc_out) {
  __shared__ short kv[Dsz * Dsz];    // 32KB: K tile, then V^T tile
  __shared__ short pbuf[Dsz * Dsz];  // 32KB: P = exp(S) in bf16

  const int b = blockIdx.x;
  const int qt = blockIdx.y;
  const int t = threadIdx.x;
  const int w = t >> 6;
  const int lane = t & 63;
  const int quad = lane >> 4;
  const int l15 = lane & 15;
  const int wq = w & 1, wk = w >> 1;

  // Q fragments (A-operand layout: A[m=lane&15][k=quad*8+j]), kept in registers
  bf16x8 aq[4][4];
  {
    const int qrow0 = b * Ssz + qt * 128 + wq * 64;
    #pragma unroll
    for (int mi = 0; mi < 4; ++mi)
      #pragma unroll
      for (int kc = 0; kc < 4; ++kc)
        aq[mi][kc] = *(const bf16x8*)&Qb[(qrow0 + mi * 16 + l15) * Dsz + kc * 32 + quad * 8];
  }

  f32x4 zero4 = {0.f, 0.f, 0.f, 0.f};
  f32x4 of[4][4];
  float rs[4][4];
  #pragma unroll
  for (int mi = 0; mi < 4; ++mi)
    #pragma unroll
    for (int ni = 0; ni < 4; ++ni) of[mi][ni] = zero4;
  #pragma unroll
  for (int mi = 0; mi < 4; ++mi)
    #pragma unroll
    for (int r = 0; r < 4; ++r) rs[mi][r] = 0.f;

  for (int it = 0; it < 32; ++it) {
    const int k0 = it * 128;

    // ---- stage K tile (swizzled write) ----
    {
      const short* src = &Kb[(b * Ssz + k0) * Dsz];
      #pragma unroll
      for (int p = 0; p < 8; ++p) {
        int sl = p * 256 + t;
        int row = sl >> 4, gp = sl & 15;
        bf16x8 tmp = *(const bf16x8*)&src[(row << 7) + (gp << 3)];
        *(bf16x8*)&kv[SWZ(row, gp)] = tmp;
      }
    }
    __syncthreads();

    // ---- QK^T : S[64q x 64k] for this wave ----
    f32x4 sc[4][4];
    #pragma unroll
    for (int mi = 0; mi < 4; ++mi)
      #pragma unroll
      for (int ni = 0; ni < 4; ++ni) sc[mi][ni] = zero4;

    #pragma unroll
    for (int kc = 0; kc < 4; ++kc) {
      #pragma unroll
      for (int ni = 0; ni < 4; ++ni) {
        int krow = wk * 64 + ni * 16 + l15;
        bf16x8 kf = *(const bf16x8*)&kv[SWZ(krow, kc * 4 + quad)];
        #pragma unroll
        for (int mi = 0; mi < 4; ++mi)
          sc[mi][ni] = __builtin_amdgcn_mfma_f32_16x16x32_bf16(aq[mi][kc], kf, sc[mi][ni], 0, 0, 0);
      }
    }

    // ---- p = exp2(s) (Q pre-scaled by log2e) ; rowsum ; write P to LDS (C->A transpose) ----
    #pragma unroll
    for (int mi = 0; mi < 4; ++mi) {
      #pragma unroll
      for (int ni = 0; ni < 4; ++ni) {
        #pragma unroll
        for (int r = 0; r < 4; ++r) {
          float p = __builtin_amdgcn_exp2f(sc[mi][ni][r]);
          rs[mi][r] += p;
          int qrow = wq * 64 + mi * 16 + quad * 4 + r;
          int kcol = wk * 64 + ni * 16 + l15;
          pbuf[(qrow << 7) + ((((kcol >> 3) ^ (qrow & 15))) << 3) + (kcol & 7)] = f2bf(p);
        }
      }
    }
    __syncthreads();  // K reads done, P visible to all waves

    // ---- stage V^T tile (rows = d, cols = keys; already transposed in global) ----
    {
      const short* src = &Vt[(b * Dsz) * Ssz + k0];
      #pragma unroll
      for (int p = 0; p < 8; ++p) {
        int sl = p * 256 + t;
        int row = sl >> 4, gp = sl & 15;
        bf16x8 tmp = *(const bf16x8*)&src[row * Ssz + (gp << 3)];
        *(bf16x8*)&kv[SWZ(row, gp)] = tmp;
      }
    }
    __syncthreads();

    // ---- PV : O[64q x 64d] += P[64q x 128k] * V[128k x 64d] ----
    #pragma unroll
    for (int kc = 0; kc < 4; ++kc) {
      bf16x8 pa[4];
      #pragma unroll
      for (int mi = 0; mi < 4; ++mi) {
        int qrow = wq * 64 + mi * 16 + l15;
        pa[mi] = *(const bf16x8*)&pbuf[SWZ(qrow, kc * 4 + quad)];
      }
      #pragma unroll
      for (int ni = 0; ni < 4; ++ni) {
        int drow = wk * 64 + ni * 16 + l15;
        bf16x8 vf = *(const bf16x8*)&kv[SWZ(drow, kc * 4 + quad)];
        #pragma unroll
        for (int mi = 0; mi < 4; ++mi)
          of[mi][ni] = __builtin_amdgcn_mfma_f32_16x16x32_bf16(pa[mi], vf, of[mi][ni], 0, 0, 0);
      }
    }
    __syncthreads();  // V reads done before next K staging
  }

  // ---- rowsum: reduce over the 16 column-lanes ----
  #pragma unroll
  for (int mi = 0; mi < 4; ++mi)
    #pragma unroll
    for (int r = 0; r < 4; ++r) {
      float v = rs[mi][r];
      v += __shfl_xor(v, 1, 64);
      v += __shfl_xor(v, 2, 64);
      v += __shfl_xor(v, 4, 64);
      v += __shfl_xor(v, 8, 64);
      rs[mi][r] = v;
    }

  // combine the two k-half waves via LDS (kv is dead now)
  float* rsf = (float*)kv;
  if (l15 == 0) {
    #pragma unroll
    for (int mi = 0; mi < 4; ++mi)
      #pragma unroll
      for (int r = 0; r < 4; ++r)
        rsf[(wq * 64 + mi * 16 + quad * 4 + r) * 2 + wk] = rs[mi][r];
  }
  __syncthreads();

  float inv[4][4];
  #pragma unroll
  for (int mi = 0; mi < 4; ++mi)
    #pragma unroll
    for (int r = 0; r < 4; ++r) {
      int q = wq * 64 + mi * 16 + quad * 4 + r;
      float l = rsf[q * 2] + rsf[q * 2 + 1];
      inv[mi][r] = 1.f / (l * (float)Ssz);  // softmax denom * mean(1/S)
    }

  // column (query-mean) reduction, then atomic add into fp32 accumulator
  #pragma unroll
  for (int ni = 0; ni < 4; ++ni) {
    float cs = 0.f;
    #pragma unroll
    for (int mi = 0; mi < 4; ++mi)
      #pragma unroll
      for (int r = 0; r < 4; ++r)
        cs += of[mi][ni][r] * inv[mi][r];
    cs += __shfl_xor(cs, 16, 64);
    cs += __shfl_xor(cs, 32, 64);
    if (lane < 16)
      atomicAdd(&acc_out[b * Dsz + wk * 64 + ni * 16 + l15], cs);
  }
}

__global__ void finalize_kernel(const float* __restrict__ acc, float* __restrict__ out) {
  int i = blockIdx.x * 256 + threadIdx.x;
  if (i < Bsz * Dsz) out[i] = acc[i];
}

extern "C" void kernel_launch(void* const* d_in, const int* in_sizes, int n_in,
                              void* d_out, int out_size, void* d_ws, size_t ws_size,
                              hipStream_t stream) {
  const float* x = (const float*)d_in[0];  // fp32 [8,4096,128]
  const float* w = (const float*)d_in[1];  // fp32 [3,128,128]
  short* Qb = (short*)d_ws;                              // 8MB bf16
  short* Kb = Qb + (size_t)Bsz * Ssz * Dsz;              // 8MB bf16
  short* Vt = Kb + (size_t)Bsz * Ssz * Dsz;              // 8MB bf16 (transposed V)
  float* acc = (float*)(Vt + (size_t)Bsz * Ssz * Dsz);   // 4KB fp32 accumulator

  proj_kernel<<<dim3(Bsz * Ssz / 16), dim3(256), 0, stream>>>(x, w, Qb, Kb, Vt);
  hipMemsetAsync(acc, 0, Bsz * Dsz * sizeof(float), stream);
  attn_kernel<<<dim3(Bsz, Ssz / 128), dim3(256), 0, stream>>>(Qb, Kb, Vt, acc);
  finalize_kernel<<<dim3((Bsz * Dsz + 255) / 256), dim3(256), 0, stream>>>(acc, (float*)d_out);
}

// Round 4
// 174.267 us; speedup vs baseline: 1.6866x; 1.6866x over previous
//
#include <hip/hip_runtime.h>
#include <hip/hip_bf16.h>

#define Bsz 8
#define Ssz 4096
#define Dsz 128

typedef short bf16x8 __attribute__((ext_vector_type(8)));
typedef short bf16x4 __attribute__((ext_vector_type(4)));
typedef float f32x4 __attribute__((ext_vector_type(4)));

__device__ __forceinline__ short f2bf(float f) {
  union { float f; unsigned u; } v; v.f = f;
  unsigned r = v.u + 0x7fffu + ((v.u >> 16) & 1u);
  return (short)(r >> 16);
}

// async global->LDS, 16B per lane: lds dest = wave-uniform base + lane*16
__device__ __forceinline__ void gll16(const void* g, void* l) {
  __builtin_amdgcn_global_load_lds((const __attribute__((address_space(1))) void*)g,
                                   (__attribute__((address_space(3))) void*)l, 16, 0, 0);
}

// Staged tile layout (bf16): per 128-row tile: [g 0..15][row 0..127][8 elems]
// Q/K: row = seq s, 8 elems = d-chunk g.  V: row = d, 8 elems = key-chunk g.

// ---------------- MFMA projection ----------------
// grid (3, 256): x = matrix (Q/K/V), y = 128-row block of X. 256 thr, 2x2 waves.
// C[128 s][128 e] = X[128 s][128 d] * W[d][e], bf16 MFMA, fp32 acc.
__global__ __launch_bounds__(256) void proj_kernel(
    const float* __restrict__ x, const float* __restrict__ w,
    short* __restrict__ Qs, short* __restrict__ Ks, short* __restrict__ Vs) {
  __shared__ short xb[16384];  // X tile, staged layout (32KB)
  __shared__ short wb[16384];  // W tile transposed: [gd][e][8 d] (32KB)

  const int mat = blockIdx.x;
  const int rb = blockIdx.y;  // 128-row block: rb = b*32 + tile
  const int t = threadIdx.x;
  const int lane = t & 63;
  const int wv = t >> 6;
  const int quad = lane >> 4;
  const int l15 = lane & 15;
  const int wq = wv & 1, wk = wv >> 1;
  const float wscale = (mat == 0) ? 1.44269504088896340736f : 1.0f;  // fold log2(e) into Wq

  // --- stage X tile: fp32 global (coalesced float4) -> bf16 LDS staged layout ---
  // 128 rows x 128 cols fp32 = 4096 float4  -> p < 16  (BUG in R3: was p < 8)
  {
    const float* xsrc = x + (size_t)rb * 128 * Dsz;
    #pragma unroll
    for (int p = 0; p < 16; ++p) {
      int idx4 = p * 256 + t;            // float4 index, 4096 per tile
      int row = idx4 >> 5;               // 32 float4 per row -> row 0..127
      int d0 = (idx4 & 31) << 2;         // 0..124, %8 in {0,4}
      f32x4 v = *(const f32x4*)&xsrc[idx4 * 4];
      bf16x4 o;
      o[0] = f2bf(v[0]); o[1] = f2bf(v[1]); o[2] = f2bf(v[2]); o[3] = f2bf(v[3]);
      *(bf16x4*)&xb[(d0 >> 3) * 1024 + row * 8 + (d0 & 7)] = o;
    }
  }
  // --- stage W[mat]: fp32 [d][e] -> LDS [gd][e][8 d] (transpose, b16 scatter) ---
  {
    const float* wsrc = w + (size_t)mat * Dsz * Dsz;
    #pragma unroll
    for (int p = 0; p < 16; ++p) {
      int idx4 = p * 256 + t;            // 4096 float4 per W matrix
      int d = idx4 >> 5;
      int e0 = (idx4 & 31) << 2;
      f32x4 v = *(const f32x4*)&wsrc[idx4 * 4];
      int base = (d >> 3) * 1024 + (d & 7);
      wb[base + (e0 + 0) * 8] = f2bf(v[0] * wscale);
      wb[base + (e0 + 1) * 8] = f2bf(v[1] * wscale);
      wb[base + (e0 + 2) * 8] = f2bf(v[2] * wscale);
      wb[base + (e0 + 3) * 8] = f2bf(v[3] * wscale);
    }
  }
  __syncthreads();

  // --- MFMA: wave (wq,wk) computes C[64 s @ wq*64][64 e @ wk*64] ---
  f32x4 acc[4][4];
  #pragma unroll
  for (int mi = 0; mi < 4; ++mi)
    #pragma unroll
    for (int ni = 0; ni < 4; ++ni) acc[mi][ni] = (f32x4){0.f, 0.f, 0.f, 0.f};

  #pragma unroll
  for (int kc = 0; kc < 4; ++kc) {
    int g = kc * 4 + quad;
    bf16x8 af[4], bf[4];
    #pragma unroll
    for (int mi = 0; mi < 4; ++mi)
      af[mi] = *(const bf16x8*)&xb[g * 1024 + (wq * 64 + mi * 16 + l15) * 8];
    #pragma unroll
    for (int ni = 0; ni < 4; ++ni)
      bf[ni] = *(const bf16x8*)&wb[g * 1024 + (wk * 64 + ni * 16 + l15) * 8];
    #pragma unroll
    for (int mi = 0; mi < 4; ++mi)
      #pragma unroll
      for (int ni = 0; ni < 4; ++ni)
        acc[mi][ni] = __builtin_amdgcn_mfma_f32_16x16x32_bf16(af[mi], bf[ni], acc[mi][ni], 0, 0, 0);
  }
  __syncthreads();  // xb dead, reuse as output tile

  // --- epilogue: C (C-layout regs) -> LDS in target staged layout -> global ---
  if (mat < 2) {
    // Q/K: staged [ge = e/8][s][8 e]
    #pragma unroll
    for (int mi = 0; mi < 4; ++mi)
      #pragma unroll
      for (int ni = 0; ni < 4; ++ni) {
        int e = wk * 64 + ni * 16 + l15;
        int base = (e >> 3) * 1024 + (e & 7);
        #pragma unroll
        for (int r = 0; r < 4; ++r) {
          int s = wq * 64 + mi * 16 + quad * 4 + r;
          xb[base + s * 8] = f2bf(acc[mi][ni][r]);
        }
      }
  } else {
    // V: staged [gs = s/8][d][8 s]  (b64-packed: 4 consecutive s per lane)
    #pragma unroll
    for (int mi = 0; mi < 4; ++mi)
      #pragma unroll
      for (int ni = 0; ni < 4; ++ni) {
        int d = wk * 64 + ni * 16 + l15;
        int sbase = wq * 64 + mi * 16;  // + quad*4 + r
        int gs = (sbase >> 3) + (quad >> 1);
        bf16x4 o;
        o[0] = f2bf(acc[mi][ni][0]); o[1] = f2bf(acc[mi][ni][1]);
        o[2] = f2bf(acc[mi][ni][2]); o[3] = f2bf(acc[mi][ni][3]);
        *(bf16x4*)&xb[gs * 1024 + d * 8 + (quad & 1) * 4] = o;
      }
  }
  __syncthreads();

  short* dst = (mat == 0 ? Qs : (mat == 1 ? Ks : Vs)) + (size_t)rb * 16384;
  #pragma unroll
  for (int p = 0; p < 8; ++p) {
    int c = p * 256 + t;
    *(bf16x8*)&dst[c * 8] = *(const bf16x8*)&xb[c * 8];
  }
}

// ---------------- Attention ----------------
// grid (8, 64): x = batch (XCD affinity -> K/V L2-local), y = 64-row q-tile.
// 4 waves: wave wk handles k-chunk [wk*32,+32) in QK^T and d-chunk [wk*32,+32) in PV.
__global__ __launch_bounds__(256, 2) void attn_kernel(
    const short* __restrict__ Qs, const short* __restrict__ Ks,
    const short* __restrict__ Vs, float* __restrict__ acc_out) {
  __shared__ short kbuf[16384];  // 32KB K tile (staged)
  __shared__ short vbuf[16384];  // 32KB V tile (staged)
  __shared__ short pbuf[8192];   // 16KB P tile: [gk][q 0..63][8 k]

  const int b = blockIdx.x;
  const int qt = blockIdx.y;
  const int t = threadIdx.x;
  const int wv = t >> 6;
  const int lane = t & 63;
  const int quad = lane >> 4;
  const int l15 = lane & 15;
  const int wk = wv;

  // Q fragments from staged global, kept in registers (A-layout)
  bf16x8 aq[4][4];
  {
    const short* qsrc = Qs + (size_t)(b * 32 + (qt >> 1)) * 16384;
    const int qbase = (qt & 1) * 64;
    #pragma unroll
    for (int mi = 0; mi < 4; ++mi)
      #pragma unroll
      for (int kc = 0; kc < 4; ++kc)
        aq[mi][kc] = *(const bf16x8*)&qsrc[((kc * 4 + quad) * 128 + qbase + mi * 16 + l15) * 8];
  }

  f32x4 of[4][2];
  float rs[4][4];
  #pragma unroll
  for (int mi = 0; mi < 4; ++mi) {
    #pragma unroll
    for (int ni = 0; ni < 2; ++ni) of[mi][ni] = (f32x4){0.f, 0.f, 0.f, 0.f};
    #pragma unroll
    for (int r = 0; r < 4; ++r) rs[mi][r] = 0.f;
  }

  const short* kt_src = Ks + (size_t)b * 32 * 16384;
  const short* vt_src = Vs + (size_t)b * 32 * 16384;

  for (int it = 0; it < 32; ++it) {
    // ---- stage K and V tiles via global_load_lds (linear, 1KB per instr) ----
    {
      const char* ksrc = (const char*)(kt_src + (size_t)it * 16384);
      const char* vsrc = (const char*)(vt_src + (size_t)it * 16384);
      #pragma unroll
      for (int p = 0; p < 8; ++p) {
        int c = wk * 8 + p;  // 1KB chunk, wave-uniform
        gll16(ksrc + c * 1024 + lane * 16, (char*)kbuf + c * 1024);
        gll16(vsrc + c * 1024 + lane * 16, (char*)vbuf + c * 1024);
      }
    }
    __syncthreads();

    // ---- QK^T: S[64q x 32k @ wk*32] ----
    f32x4 sc[4][2];
    #pragma unroll
    for (int mi = 0; mi < 4; ++mi)
      #pragma unroll
      for (int ni = 0; ni < 2; ++ni) sc[mi][ni] = (f32x4){0.f, 0.f, 0.f, 0.f};

    #pragma unroll
    for (int kc = 0; kc < 4; ++kc) {
      bf16x8 kf[2];
      #pragma unroll
      for (int ni = 0; ni < 2; ++ni)
        kf[ni] = *(const bf16x8*)&kbuf[(kc * 4 + quad) * 1024 + (wk * 32 + ni * 16 + l15) * 8];
      #pragma unroll
      for (int mi = 0; mi < 4; ++mi)
        #pragma unroll
        for (int ni = 0; ni < 2; ++ni)
          sc[mi][ni] = __builtin_amdgcn_mfma_f32_16x16x32_bf16(aq[mi][kc], kf[ni], sc[mi][ni], 0, 0, 0);
    }

    // ---- p = exp2(s); rowsum; P -> LDS (staged layout for A-frag reads) ----
    #pragma unroll
    for (int mi = 0; mi < 4; ++mi)
      #pragma unroll
      for (int ni = 0; ni < 2; ++ni) {
        int k = wk * 32 + ni * 16 + l15;
        int base = (k >> 3) * 512 + (k & 7);
        #pragma unroll
        for (int r = 0; r < 4; ++r) {
          float p = __builtin_amdgcn_exp2f(sc[mi][ni][r]);
          rs[mi][r] += p;
          int q = mi * 16 + quad * 4 + r;
          pbuf[base + q * 8] = f2bf(p);
        }
      }
    __syncthreads();  // P visible; K reads done

    // ---- PV: O[64q x 32d @ wk*32] += P[64q x 128k] * V[128k x 32d] ----
    #pragma unroll
    for (int kc = 0; kc < 4; ++kc) {
      bf16x8 pa[4], vf[2];
      #pragma unroll
      for (int mi = 0; mi < 4; ++mi)
        pa[mi] = *(const bf16x8*)&pbuf[(kc * 4 + quad) * 512 + (mi * 16 + l15) * 8];
      #pragma unroll
      for (int ni = 0; ni < 2; ++ni)
        vf[ni] = *(const bf16x8*)&vbuf[(kc * 4 + quad) * 1024 + (wk * 32 + ni * 16 + l15) * 8];
      #pragma unroll
      for (int mi = 0; mi < 4; ++mi)
        #pragma unroll
        for (int ni = 0; ni < 2; ++ni)
          of[mi][ni] = __builtin_amdgcn_mfma_f32_16x16x32_bf16(pa[mi], vf[ni], of[mi][ni], 0, 0, 0);
    }
    __syncthreads();  // V/P reads done before next staging
  }

  // ---- softmax denominators: reduce rs over 16 lanes, combine 4 waves via LDS ----
  #pragma unroll
  for (int mi = 0; mi < 4; ++mi)
    #pragma unroll
    for (int r = 0; r < 4; ++r) {
      float v = rs[mi][r];
      v += __shfl_xor(v, 1, 64);
      v += __shfl_xor(v, 2, 64);
      v += __shfl_xor(v, 4, 64);
      v += __shfl_xor(v, 8, 64);
      rs[mi][r] = v;
    }
  float* rsf = (float*)pbuf;  // 64q x 4 waves
  if (l15 == 0) {
    #pragma unroll
    for (int mi = 0; mi < 4; ++mi)
      #pragma unroll
      for (int r = 0; r < 4; ++r)
        rsf[(mi * 16 + quad * 4 + r) * 4 + wk] = rs[mi][r];
  }
  __syncthreads();

  float inv[4][4];
  #pragma unroll
  for (int mi = 0; mi < 4; ++mi)
    #pragma unroll
    for (int r = 0; r < 4; ++r) {
      int q = mi * 16 + quad * 4 + r;
      float l = rsf[q * 4] + rsf[q * 4 + 1] + rsf[q * 4 + 2] + rsf[q * 4 + 3];
      inv[mi][r] = 1.f / (l * (float)Ssz);
    }

  // ---- query-mean reduction, atomic accumulate ----
  #pragma unroll
  for (int ni = 0; ni < 2; ++ni) {
    float cs = 0.f;
    #pragma unroll
    for (int mi = 0; mi < 4; ++mi)
      #pragma unroll
      for (int r = 0; r < 4; ++r)
        cs += of[mi][ni][r] * inv[mi][r];
    cs += __shfl_xor(cs, 16, 64);
    cs += __shfl_xor(cs, 32, 64);
    if (lane < 16)
      atomicAdd(&acc_out[b * Dsz + wk * 32 + ni * 16 + lane], cs);
  }
}

__global__ void finalize_kernel(const float* __restrict__ acc, float* __restrict__ out) {
  int i = blockIdx.x * 256 + threadIdx.x;
  if (i < Bsz * Dsz) out[i] = acc[i];
}

extern "C" void kernel_launch(void* const* d_in, const int* in_sizes, int n_in,
                              void* d_out, int out_size, void* d_ws, size_t ws_size,
                              hipStream_t stream) {
  const float* x = (const float*)d_in[0];  // fp32 [8,4096,128]
  const float* w = (const float*)d_in[1];  // fp32 [3,128,128]
  short* Qs = (short*)d_ws;                             // 8MB bf16 staged
  short* Ks = Qs + (size_t)Bsz * Ssz * Dsz;             // 8MB
  short* Vs = Ks + (size_t)Bsz * Ssz * Dsz;             // 8MB
  float* acc = (float*)(Vs + (size_t)Bsz * Ssz * Dsz);  // 4KB fp32 accumulator

  proj_kernel<<<dim3(3, 256), dim3(256), 0, stream>>>(x, w, Qs, Ks, Vs);
  hipMemsetAsync(acc, 0, Bsz * Dsz * sizeof(float), stream);
  attn_kernel<<<dim3(Bsz, 64), dim3(256), 0, stream>>>(Qs, Ks, Vs, acc);
  finalize_kernel<<<dim3((Bsz * Dsz + 255) / 256), dim3(256), 0, stream>>>(acc, (float*)d_out);
}